// Round 4
// baseline (12.120 us; speedup 1.0000x reference)
//
#include <hip/hip_runtime.h>
#include <hip/hip_bf16.h>

#define HD_D   2048
#define NW     32      // 2048 bits = 32 x uint64
#define NQ     16      // levels
#define NF     40      // features
#define NB     8       // batch
#define NT     128     // time steps

typedef unsigned long long u64;

// Fully fused: grid = NB*NW = 256 blocks (one per CU), 512 threads.
// Block (b, w) computes output bits d in [w*64, w*64+64) for batch b.
// Since T=128, tw = t>>6 is only 0 or 1, so word w of the rolled row only
// ever touches source words {w-2, w-1, w}: each block packs just 56 rows
// x 3 words itself. Time is split into 8 octants of 16 steps (320 threads
// in the main loop) to halve the serial LDS-dependent chain.
__global__ __launch_bounds__(512)
void enc_fused(const float* __restrict__ x,
               const int* __restrict__ level_hvs,
               const int* __restrict__ id_hvs,
               float* __restrict__ out)
{
    __shared__ u64 lvlw[NQ][3];            // level rows, slots = words (w-2, w-1, w)
    __shared__ u64 idw[NF][3];             // id rows, same 3 slots
    __shared__ unsigned char qidx[NT * NF];// quantized x[b], layout [t][f]
    __shared__ u64 partial[NF * 8];        // (f, octant) partial XORs
    __shared__ u64 seqw[NF];               // per-f seq word at this w

    const int b   = blockIdx.x >> 5;
    const int w   = blockIdx.x & 31;
    const int tid = threadIdx.x;

    // ---- quantize x[b]: 5120 floats as 1280 float4 (coalesced) ----
    const float4* xb = (const float4*)(x + b * NT * NF);
    #pragma unroll
    for (int r = 0; r < 3; ++r) {
        const int i4 = tid + r * 512;
        if (i4 < 1280) {
            const float4 v = xb[i4];
            unsigned int p;
            p  = ((unsigned)(((int)(v.x * 16.0f - 1.0f) + 16) & 15));
            p |= ((unsigned)(((int)(v.y * 16.0f - 1.0f) + 16) & 15)) << 8;
            p |= ((unsigned)(((int)(v.z * 16.0f - 1.0f) + 16) & 15)) << 16;
            p |= ((unsigned)(((int)(v.w * 16.0f - 1.0f) + 16) & 15)) << 24;
            *(unsigned int*)(qidx + i4 * 4) = p;
        }
    }

    // ---- pack the 56x3 needed HV words; one thread per word ----
    if (tid >= 512 - (NQ + NF) * 3) {       // use the upper waves (quantize tail is in lower)
        const int pi   = tid - (512 - (NQ + NF) * 3);
        const int row  = pi / 3;             // 0..55
        const int slot = pi % 3;             // word col (w-2+slot) & 31
        const int col  = (w + slot - 2) & (NW - 1);
        const int* src = (row < NQ)
            ? (level_hvs + row * HD_D + col * 64)
            : (id_hvs + (row - NQ) * HD_D + col * 64);
        const int4* s4 = (const int4*)src;
        u64 v = 0;
        #pragma unroll
        for (int c = 0; c < 16; ++c) {
            const int4 e = s4[c];
            v |= ((u64)(e.x & 1)) << (c * 4 + 0);
            v |= ((u64)(e.y & 1)) << (c * 4 + 1);
            v |= ((u64)(e.z & 1)) << (c * 4 + 2);
            v |= ((u64)(e.w & 1)) << (c * 4 + 3);
        }
        if (row < NQ) lvlw[row][slot] = v;
        else          idw[row - NQ][slot] = v;
    }
    __syncthreads();

    // ---- seq: tid = f*8 + oct, oct = 16-step time octant ----
    if (tid < NF * 8) {
        const int f   = tid >> 3;
        const int oct = tid & 7;
        const int t0  = oct * 16;
        const int tw  = oct >> 2;        // t>>6, constant over the octant
        const int i1  = 2 - tw;          // slot of word j  = (w - tw) & 31
        const int i2  = 1 - tw;          // slot of word j2 = (w - tw - 1) & 31
        const u64 ih1 = idw[f][i1];
        const u64 ih2 = idw[f][i2];
        u64 acc = 0ULL;
        #pragma unroll
        for (int k = 0; k < 16; ++k) {
            const int t  = t0 + k;
            const int tb = ((oct & 3) << 4) | k;   // t & 63
            const int li = qidx[t * NF + f];
            const u64 r1 = lvlw[li][i1] ^ ih1;
            const u64 r2 = lvlw[li][i2] ^ ih2;
            const u64 lo = tb ? (r2 >> ((64 - tb) & 63)) : 0ULL;
            acc ^= (r1 << tb) | lo;
        }
        partial[tid] = acc;
    }
    __syncthreads();

    if (tid < NF) {
        const u64* p = partial + tid * 8;
        seqw[tid] = p[0] ^ p[1] ^ p[2] ^ p[3] ^ p[4] ^ p[5] ^ p[6] ^ p[7];
    }
    __syncthreads();

    // ---- bundle over features + hard quantize; 64 contiguous floats ----
    if (tid < 64) {
        int cnt = 0;
        #pragma unroll
        for (int f = 0; f < NF; ++f)
            cnt += (int)((seqw[f] >> tid) & 1ULL);   // broadcast LDS reads
        out[b * HD_D + w * 64 + tid] = (cnt > 20) ? 1.0f : -1.0f;
    }
}

extern "C" void kernel_launch(void* const* d_in, const int* in_sizes, int n_in,
                              void* d_out, int out_size, void* d_ws, size_t ws_size,
                              hipStream_t stream)
{
    const float* x         = (const float*)d_in[0];  // [8,128,40] f32
    const int*   level_hvs = (const int*)d_in[1];    // [16,2048] i32
    const int*   id_hvs    = (const int*)d_in[2];    // [40,2048] i32
    float*       out       = (float*)d_out;          // [8,2048] f32

    enc_fused<<<NB * NW, 512, 0, stream>>>(x, level_hvs, id_hvs, out);
}

// Round 5
// 10.043 us; speedup vs baseline: 1.2068x; 1.2068x over previous
//
#include <hip/hip_runtime.h>
#include <hip/hip_bf16.h>

#define HD_D   2048
#define NW     32      // 2048 bits = 32 x uint64
#define NQ     16      // levels
#define NF     40      // features
#define NB     8       // batch
#define NT     128     // time steps

typedef unsigned long long u64;

// Fully fused: grid = NB*NW = 256 blocks (one per CU), 256 threads.
// Block (b, w) computes output bits d in [w*64, w*64+64) for batch b.
// Since T=128, tw = t>>6 is only 0 or 1, so word w of the rolled row only
// ever touches source words {w-2, w-1, w}: each block packs just 56 rows
// x 3 words itself (per-thread int4 loads — no cross-block handoff).
//
// Measured: single dispatch, body ~1-3 us, dur_us ~11 ~= graph-replay launch
// floor. 512-thread variant regressed (12.1 us); keep 256.
__global__ __launch_bounds__(256)
void enc_fused(const float* __restrict__ x,
               const int* __restrict__ level_hvs,
               const int* __restrict__ id_hvs,
               float* __restrict__ out)
{
    __shared__ u64 lvlw[NQ][3];            // level rows, slots = words (w-2, w-1, w)
    __shared__ u64 idw[NF][3];             // id rows, same 3 slots
    __shared__ unsigned char qidx[NT * NF];// quantized x[b], layout [t][f]
    __shared__ u64 partial[160];           // (f, quarter) partial XORs
    __shared__ u64 seqw[NF];               // per-f seq word at this w

    const int b   = blockIdx.x >> 5;
    const int w   = blockIdx.x & 31;
    const int tid = threadIdx.x;

    // ---- quantize x[b]: 5120 floats as 1280 float4 (coalesced) ----
    const float4* xb = (const float4*)(x + b * NT * NF);
    #pragma unroll
    for (int r = 0; r < 5; ++r) {
        const int i4 = tid + r * 256;
        const float4 v = xb[i4];
        unsigned int p;
        p  = ((unsigned)(((int)(v.x * 16.0f - 1.0f) + 16) & 15));
        p |= ((unsigned)(((int)(v.y * 16.0f - 1.0f) + 16) & 15)) << 8;
        p |= ((unsigned)(((int)(v.z * 16.0f - 1.0f) + 16) & 15)) << 16;
        p |= ((unsigned)(((int)(v.w * 16.0f - 1.0f) + 16) & 15)) << 24;
        *(unsigned int*)(qidx + i4 * 4) = p;
    }

    // ---- pack the 56x3 needed HV words; one thread per word ----
    if (tid < (NQ + NF) * 3) {
        const int row  = tid / 3;               // 0..55
        const int slot = tid % 3;                // word col (w-2+slot) & 31
        const int col  = (w + slot - 2) & (NW - 1);
        const int* src = (row < NQ)
            ? (level_hvs + row * HD_D + col * 64)
            : (id_hvs + (row - NQ) * HD_D + col * 64);
        const int4* s4 = (const int4*)src;
        u64 v = 0;
        #pragma unroll
        for (int c = 0; c < 16; ++c) {
            const int4 e = s4[c];
            v |= ((u64)(e.x & 1)) << (c * 4 + 0);
            v |= ((u64)(e.y & 1)) << (c * 4 + 1);
            v |= ((u64)(e.z & 1)) << (c * 4 + 2);
            v |= ((u64)(e.w & 1)) << (c * 4 + 3);
        }
        if (row < NQ) lvlw[row][slot] = v;
        else          idw[row - NQ][slot] = v;
    }
    __syncthreads();

    // ---- seq: tid = f*4 + q, q = 32-step time quarter ----
    if (tid < NF * 4) {
        const int f  = tid >> 2;
        const int q  = tid & 3;
        const int t0 = q * 32;
        const int tw = q >> 1;           // t>>6, constant over the quarter
        const int i1 = 2 - tw;           // slot of word j  = (w - tw) & 31
        const int i2 = 1 - tw;           // slot of word j2 = (w - tw - 1) & 31
        const u64 ih1 = idw[f][i1];
        const u64 ih2 = idw[f][i2];
        u64 acc = 0ULL;
        for (int k = 0; k < 32; ++k) {
            const int t  = t0 + k;
            const int tb = ((q & 1) << 5) | k;     // t & 63
            const int li = qidx[t * NF + f];
            const u64 r1 = lvlw[li][i1] ^ ih1;
            const u64 r2 = lvlw[li][i2] ^ ih2;
            const u64 lo = tb ? (r2 >> ((64 - tb) & 63)) : 0ULL;
            acc ^= (r1 << tb) | lo;
        }
        partial[tid] = acc;
    }
    __syncthreads();

    if (tid < NF)
        seqw[tid] = partial[tid * 4] ^ partial[tid * 4 + 1]
                  ^ partial[tid * 4 + 2] ^ partial[tid * 4 + 3];
    __syncthreads();

    // ---- bundle over features + hard quantize; 64 contiguous floats ----
    if (tid < 64) {
        int cnt = 0;
        #pragma unroll
        for (int f = 0; f < NF; ++f)
            cnt += (int)((seqw[f] >> tid) & 1ULL);   // broadcast LDS reads
        out[b * HD_D + w * 64 + tid] = (cnt > 20) ? 1.0f : -1.0f;
    }
}

extern "C" void kernel_launch(void* const* d_in, const int* in_sizes, int n_in,
                              void* d_out, int out_size, void* d_ws, size_t ws_size,
                              hipStream_t stream)
{
    const float* x         = (const float*)d_in[0];  // [8,128,40] f32
    const int*   level_hvs = (const int*)d_in[1];    // [16,2048] i32
    const int*   id_hvs    = (const int*)d_in[2];    // [40,2048] i32
    float*       out       = (float*)d_out;          // [8,2048] f32

    enc_fused<<<NB * NW, 256, 0, stream>>>(x, level_hvs, id_hvs, out);
}